// Round 12
// baseline (165.519 us; speedup 1.0000x reference)
//
#include <hip/hip_runtime.h>
#include <math.h>

// FBPINN PoU: S=64 subdomains, N=65536 points, W=64.
// Round 12: single fused kernel (256 blocks x 256 thr) with 2 software grid
// barriers. r11 showed a 4x work cut gains only 2.7 us -> the controllable
// time is launch/gap overhead (3 dependent graph nodes), not work. 256
// blocks with 4 blocks/CU capacity => provably co-resident => sense-reversing
// spin barrier on __device__ globals is safe (self-resets each replay).
//   Phase A: r11 eval_grid verbatim (MFMA f16, GK=1280, WIDTH=256).
//   Phase B: ftable (u_corr on GF=4096 grid), 12-way parallel + LDS reduce.
//   Phase C: apply, F staged to LDS (coalesced) then per-point lerp.

#define GK     1280
#define WIDTH  256
#define HALFW  128
#define SW     36      // u32 words per LDS row: 32 data + 4 pad = 144 B
#define GF     4096    // final-function table resolution
#define NB     256     // grid blocks (must match launch!)

typedef _Float16 half8  __attribute__((ext_vector_type(8)));
typedef __fp16   fp16x2 __attribute__((ext_vector_type(2)));
typedef float    f32x4  __attribute__((ext_vector_type(4)));

__device__ unsigned g_count = 0;
__device__ unsigned g_sense = 0;

__device__ __forceinline__ void grid_barrier() {
    __threadfence();                       // release prior global writes
    __syncthreads();
    if (threadIdx.x == 0) {
        unsigned my  = __hip_atomic_load(&g_sense, __ATOMIC_RELAXED,
                                         __HIP_MEMORY_SCOPE_AGENT);
        unsigned old = __hip_atomic_fetch_add(&g_count, 1u, __ATOMIC_ACQ_REL,
                                              __HIP_MEMORY_SCOPE_AGENT);
        if (old == NB - 1u) {
            __hip_atomic_store(&g_count, 0u, __ATOMIC_RELAXED,
                               __HIP_MEMORY_SCOPE_AGENT);
            __hip_atomic_fetch_add(&g_sense, 1u, __ATOMIC_RELEASE,
                                   __HIP_MEMORY_SCOPE_AGENT);
        } else {
            while (__hip_atomic_load(&g_sense, __ATOMIC_ACQUIRE,
                                     __HIP_MEMORY_SCOPE_AGENT) == my)
                __builtin_amdgcn_s_sleep(2);
        }
    }
    __syncthreads();
    __threadfence();                       // acquire side
}

__device__ __forceinline__ int glo_of(int s) {
    int g = (s * GK + 31) / 63 - HALFW;
    g = g < 0 ? 0 : g;
    const int hi = GK - (WIDTH - 1);
    g = g > hi ? hi : g;
    return g;
}

__device__ __forceinline__ float tanh_fast(float v) {
    float e = __expf(2.0f * v);
    return 1.0f - 2.0f * __builtin_amdgcn_rcpf(e + 1.0f);
}

__device__ __forceinline__ unsigned pkh(float a, float b) {
    fp16x2 h = __builtin_amdgcn_cvt_pkrtz(a, b);   // a->lo, b->hi
    return __builtin_bit_cast(unsigned, h);
}

// ---------------------------------------------------------------------------
__global__ __launch_bounds__(256, 4) void fbpinn_fused(
    const float* __restrict__ x_in,
    const float* __restrict__ W0, const float* __restrict__ b0,
    const float* __restrict__ W1, const float* __restrict__ b1,
    const float* __restrict__ W2, const float* __restrict__ b2,
    const float* __restrict__ W3, const float* __restrict__ b3,
    float* __restrict__ U, float* __restrict__ Fg,
    float* __restrict__ out)
{
    const int tid  = (int)threadIdx.x;
    const int b    = (int)blockIdx.x;
    const int lane = tid & 63;
    const int wv   = __builtin_amdgcn_readfirstlane(tid >> 6);
    const int quad = lane >> 4;
    const int a16  = lane & 15;

    // One flat LDS pool, phase-aliased (phases separated by barriers).
    __shared__ __align__(16) unsigned char SMEM[38912];
    unsigned* HtA = (unsigned*)SMEM;            // 9216 B
    unsigned* HtB = HtA + 64 * SW;              // 9216 B
    unsigned* Wa1 = HtB + 64 * SW;              // 9216 B
    unsigned* Wa2 = Wa1 + 64 * SW;              // 9216 B
    float*    Pw  = (float*)(Wa2 + 64 * SW);    // 4*4*16 floats = 1024 B
    // Phase B aliases (dead phase-A regions):
    float* Fnum = (float*)(SMEM + 20480);       // [17][13]
    float* Fden = (float*)(SMEM + 22528);       // [17][13]
    // Phase C alias:
    float* Fl   = (float*)SMEM;                 // 4097 floats = 16388 B

    // ===================== Phase A: eval (r11 verbatim) ====================
    {
        const int s     = b & 63;
        const int chunk = b >> 6;              // 0..3
        const int glo   = glo_of(s);
        const float x   = (float)(glo + chunk * 64 + lane) * (1.0f / (float)GK);

        const float4* __restrict__ g1 = (const float4*)(W1 + s * 4096);
        const float4* __restrict__ g2 = (const float4*)(W2 + s * 4096);
#pragma unroll
        for (int q = 0; q < 4; ++q) {
            int li = q * 256 + tid;
            int v  = li >> 4;
            int wd = 2 * (li & 15);
            float4 f1 = g1[li];
            float4 f2 = g2[li];
            Wa1[v * SW + wd]     = pkh(f1.x, f1.y);
            Wa1[v * SW + wd + 1] = pkh(f1.z, f1.w);
            Wa2[v * SW + wd]     = pkh(f2.x, f2.y);
            Wa2[v * SW + wd + 1] = pkh(f2.z, f2.w);
        }

        const float* __restrict__ w0  = W0 + s * 64;
        const float* __restrict__ bb0 = b0 + s * 64;
#pragma unroll
        for (int j = 0; j < 16; j += 2) {
            int v = 16 * wv + j;
            float h0 = tanh_fast(fmaf(w0[v],     x, bb0[v]));
            float h1 = tanh_fast(fmaf(w0[v + 1], x, bb0[v + 1]));
            HtA[lane * SW + (v >> 1)] = pkh(h0, h1);
        }
        __syncthreads();

        const int vbase = 16 * wv + 4 * quad;
        f32x4 acc[4];

        // ---- layer 1
        {
            const float* __restrict__ b1g = b1 + s * 64;
            float bv[4];
#pragma unroll
            for (int r = 0; r < 4; ++r) bv[r] = b1g[vbase + r];
#pragma unroll
            for (int ni = 0; ni < 4; ++ni)
#pragma unroll
                for (int r = 0; r < 4; ++r) acc[ni][r] = bv[r];

            half8 afr[2];
#pragma unroll
            for (int ks = 0; ks < 2; ++ks)
                afr[ks] = *(const half8*)&Wa1[(16 * wv + a16) * SW + 16 * ks + 4 * quad];
#pragma unroll
            for (int ni = 0; ni < 4; ++ni) {
#pragma unroll
                for (int ks = 0; ks < 2; ++ks) {
                    half8 bfr = *(const half8*)&HtA[(16 * ni + a16) * SW + 16 * ks + 4 * quad];
                    acc[ni] = __builtin_amdgcn_mfma_f32_16x16x32_f16(afr[ks], bfr, acc[ni], 0, 0, 0);
                }
            }
#pragma unroll
            for (int ni = 0; ni < 4; ++ni) {
                int row  = (16 * ni + a16) * SW;
                int colb = 8 * wv + 2 * quad;
                HtB[row + colb]     = pkh(tanh_fast(acc[ni][0]), tanh_fast(acc[ni][1]));
                HtB[row + colb + 1] = pkh(tanh_fast(acc[ni][2]), tanh_fast(acc[ni][3]));
            }
        }
        __syncthreads();

        // ---- layer 2
        {
            const float* __restrict__ b2g = b2 + s * 64;
            float bv[4];
#pragma unroll
            for (int r = 0; r < 4; ++r) bv[r] = b2g[vbase + r];
#pragma unroll
            for (int ni = 0; ni < 4; ++ni)
#pragma unroll
                for (int r = 0; r < 4; ++r) acc[ni][r] = bv[r];

            half8 afr[2];
#pragma unroll
            for (int ks = 0; ks < 2; ++ks)
                afr[ks] = *(const half8*)&Wa2[(16 * wv + a16) * SW + 16 * ks + 4 * quad];
#pragma unroll
            for (int ni = 0; ni < 4; ++ni) {
#pragma unroll
                for (int ks = 0; ks < 2; ++ks) {
                    half8 bfr = *(const half8*)&HtB[(16 * ni + a16) * SW + 16 * ks + 4 * quad];
                    acc[ni] = __builtin_amdgcn_mfma_f32_16x16x32_f16(afr[ks], bfr, acc[ni], 0, 0, 0);
                }
            }
        }

        // ---- layer 3
        {
            const float* __restrict__ w3g = W3 + s * 64;
            float w3r[4];
#pragma unroll
            for (int r = 0; r < 4; ++r) w3r[r] = w3g[vbase + r];
#pragma unroll
            for (int ni = 0; ni < 4; ++ni) {
                float pu = 0.0f;
#pragma unroll
                for (int r = 0; r < 4; ++r)
                    pu = fmaf(w3r[r], tanh_fast(acc[ni][r]), pu);
                pu += __shfl_xor(pu, 16);
                pu += __shfl_xor(pu, 32);
                if (quad == 0) Pw[(wv * 4 + ni) * 16 + a16] = pu;
            }
        }
        __syncthreads();

        if (tid < 64) {
            float u = b3[s];
#pragma unroll
            for (int w = 0; w < 4; ++w) u += Pw[(w * 4 + (tid >> 4)) * 16 + (tid & 15)];
            U[s * WIDTH + chunk * 64 + tid] = u;
        }
    }

    grid_barrier();                             // U visible everywhere

    // ===================== Phase B: build F table ==========================
    {
        const int lim = (b == NB - 1) ? 204 : 192;   // 17 or 16 entries x 12
        if (tid < lim) {
            int e = tid / 12;
            int k = tid % 12;
            int g = b * 16 + e;                      // 0..4096
            float x = (float)g * (1.0f / (float)GF);

            int jf = (int)floorf(x * 63.0f);
            int lo = jf - 5;
            lo = lo < 0 ? 0 : (lo > 52 ? 52 : lo);
            int s = lo + k;

            const float inv_sigma = 64.0f / 1.5f;
            float t = x * (float)GK - (float)glo_of(s);
            int it = (int)floorf(t);
            it = it < 0 ? 0 : (it > WIDTH - 2 ? WIDTH - 2 : it);
            float frac = t - (float)it;
            const float* __restrict__ row = U + s * WIDTH + it;
            float u0 = row[0];
            float u1 = row[1];
            float u = fmaf(frac, u1 - u0, u0);
            float d = (x - (float)s * (1.0f / 63.0f)) * inv_sigma;
            float w = __expf(-0.5f * d * d);
            Fnum[e * 13 + k] = w * u;
            Fden[e * 13 + k] = w;
        }
        __syncthreads();
        const int lim2 = (b == NB - 1) ? 17 : 16;
        if (tid < lim2) {
            float num = 0.0f, den = 0.0f;
#pragma unroll
            for (int k = 0; k < 12; ++k) {
                num += Fnum[tid * 13 + k];
                den += Fden[tid * 13 + k];
            }
            Fg[b * 16 + tid] = num * __builtin_amdgcn_rcpf(den);
        }
    }

    grid_barrier();                             // F visible everywhere

    // ===================== Phase C: apply ==================================
    {
        // stage F (16 KB) into LDS, coalesced
#pragma unroll
        for (int q = 0; q < 16; ++q) Fl[q * 256 + tid] = Fg[q * 256 + tid];
        if (tid == 0) Fl[GF] = Fg[GF];
        __syncthreads();

        int n = b * 256 + tid;
        float x = x_in[n];
        float t = x * (float)GF;
        int it = (int)floorf(t);
        it = it < 0 ? 0 : (it > GF - 1 ? GF - 1 : it);
        float frac = t - (float)it;
        float f0 = Fl[it];
        float f1 = Fl[it + 1];
        float uc = fmaf(frac, f1 - f0, f0);
        out[n] = tanh_fast(5.0f * x) * uc;
    }
}

// ---------------------------------------------------------------------------
extern "C" void kernel_launch(void* const* d_in, const int* in_sizes, int n_in,
                              void* d_out, int out_size, void* d_ws, size_t ws_size,
                              hipStream_t stream) {
    const float* x  = (const float*)d_in[0];
    const float* W0 = (const float*)d_in[1];
    const float* b0 = (const float*)d_in[2];
    const float* W1 = (const float*)d_in[3];
    const float* b1 = (const float*)d_in[4];
    const float* W2 = (const float*)d_in[5];
    const float* b2 = (const float*)d_in[6];
    const float* W3 = (const float*)d_in[7];
    const float* b3 = (const float*)d_in[8];

    float* U   = (float*)d_ws;              // 64*256*4 B = 64 KiB
    float* F   = U + 64 * WIDTH;            // (GF+1)*4 B = 16 KiB
    float* out = (float*)d_out;

    fbpinn_fused<<<dim3(NB), dim3(256), 0, stream>>>(
        x, W0, b0, W1, b1, W2, b2, W3, b3, U, F, out);
}

// Round 13
// 125.124 us; speedup vs baseline: 1.3228x; 1.3228x over previous
//
#include <hip/hip_runtime.h>
#include <math.h>

// FBPINN PoU: S=64 subdomains, N=65536 points, W=64.
// Round 13: single fused kernel, ONE hierarchical grid barrier.
//   r12's flat barrier collapsed (255 uncached pollers on one line ->
//   home-L2 same-line queue saturation -> ~50 us/barrier, VALUBusy 1%).
//   Fix: 2-level sense barrier (16 groups x 16 blocks, 128B-padded lines,
//   s_sleep(8) polls; <=16 pollers/line) + drop the F-table phase so only
//   ONE barrier remains (phase C combines directly from global U, which
//   also removes the F-lerp error term).
//   Phase A: r11 eval_grid verbatim (MFMA f16, GK=1280, WIDTH=256).
//   Phase C: per-point 12-subnet Gaussian PoU combine + hard BC (r9 math).
// Co-residency: 256 blocks, 38.9 KB LDS (cap 4/CU), VGPR ~52 -> 1 block/CU.

#define GK     1280
#define WIDTH  256
#define HALFW  128
#define SW     36      // u32 words per LDS row: 32 data + 4 pad = 144 B
#define NB     256     // grid blocks (must match launch!)

typedef _Float16 half8  __attribute__((ext_vector_type(8)));
typedef __fp16   fp16x2 __attribute__((ext_vector_type(2)));
typedef float    f32x4  __attribute__((ext_vector_type(4)));

struct __align__(128) BarLine { unsigned cnt; unsigned sense; unsigned pad[30]; };
__device__ BarLine g_grp[16];   // zero-init; cnt self-resets, sense monotonic
__device__ BarLine g_glob;

__device__ __forceinline__ void grid_barrier(int b) {
    __threadfence();                       // release prior global writes
    __syncthreads();
    if (threadIdx.x == 0) {
        const int g = b >> 4;
        unsigned my  = __hip_atomic_load(&g_grp[g].sense, __ATOMIC_RELAXED,
                                         __HIP_MEMORY_SCOPE_AGENT);
        unsigned old = __hip_atomic_fetch_add(&g_grp[g].cnt, 1u, __ATOMIC_ACQ_REL,
                                              __HIP_MEMORY_SCOPE_AGENT);
        if (old == 15u) {                  // group leader (last arriver)
            __hip_atomic_store(&g_grp[g].cnt, 0u, __ATOMIC_RELAXED,
                               __HIP_MEMORY_SCOPE_AGENT);
            unsigned gmy  = __hip_atomic_load(&g_glob.sense, __ATOMIC_RELAXED,
                                              __HIP_MEMORY_SCOPE_AGENT);
            unsigned gold = __hip_atomic_fetch_add(&g_glob.cnt, 1u, __ATOMIC_ACQ_REL,
                                                   __HIP_MEMORY_SCOPE_AGENT);
            if (gold == 15u) {
                __hip_atomic_store(&g_glob.cnt, 0u, __ATOMIC_RELAXED,
                                   __HIP_MEMORY_SCOPE_AGENT);
                __hip_atomic_fetch_add(&g_glob.sense, 1u, __ATOMIC_RELEASE,
                                       __HIP_MEMORY_SCOPE_AGENT);
            } else {
                while (__hip_atomic_load(&g_glob.sense, __ATOMIC_ACQUIRE,
                                         __HIP_MEMORY_SCOPE_AGENT) == gmy)
                    __builtin_amdgcn_s_sleep(8);
            }
            __hip_atomic_fetch_add(&g_grp[g].sense, 1u, __ATOMIC_RELEASE,
                                   __HIP_MEMORY_SCOPE_AGENT);
        } else {
            while (__hip_atomic_load(&g_grp[g].sense, __ATOMIC_ACQUIRE,
                                     __HIP_MEMORY_SCOPE_AGENT) == my)
                __builtin_amdgcn_s_sleep(8);
        }
    }
    __syncthreads();
    __threadfence();                       // acquire side
}

__device__ __forceinline__ int glo_of(int s) {
    int g = (s * GK + 31) / 63 - HALFW;
    g = g < 0 ? 0 : g;
    const int hi = GK - (WIDTH - 1);
    g = g > hi ? hi : g;
    return g;
}

__device__ __forceinline__ float tanh_fast(float v) {
    float e = __expf(2.0f * v);
    return 1.0f - 2.0f * __builtin_amdgcn_rcpf(e + 1.0f);
}

__device__ __forceinline__ unsigned pkh(float a, float b) {
    fp16x2 h = __builtin_amdgcn_cvt_pkrtz(a, b);   // a->lo, b->hi
    return __builtin_bit_cast(unsigned, h);
}

// ---------------------------------------------------------------------------
__global__ __launch_bounds__(256, 4) void fbpinn_fused(
    const float* __restrict__ x_in,
    const float* __restrict__ W0, const float* __restrict__ b0,
    const float* __restrict__ W1, const float* __restrict__ b1,
    const float* __restrict__ W2, const float* __restrict__ b2,
    const float* __restrict__ W3, const float* __restrict__ b3,
    float* __restrict__ U, float* __restrict__ out)
{
    const int tid  = (int)threadIdx.x;
    const int b    = (int)blockIdx.x;
    const int lane = tid & 63;
    const int wv   = __builtin_amdgcn_readfirstlane(tid >> 6);
    const int quad = lane >> 4;
    const int a16  = lane & 15;

    __shared__ unsigned HtA[64 * SW];   // h0, f16-pairs, rows = p
    __shared__ unsigned HtB[64 * SW];   // h1
    __shared__ unsigned Wa1[64 * SW];   // W1 f16, rows = v (A layout)
    __shared__ unsigned Wa2[64 * SW];
    __shared__ float    Pw[4][4][16];   // layer-3 partials

    // ===================== Phase A: eval (r11 verbatim) ====================
    {
        const int s     = b & 63;
        const int chunk = b >> 6;              // 0..3
        const int glo   = glo_of(s);
        const float x   = (float)(glo + chunk * 64 + lane) * (1.0f / (float)GK);

        const float4* __restrict__ g1 = (const float4*)(W1 + s * 4096);
        const float4* __restrict__ g2 = (const float4*)(W2 + s * 4096);
#pragma unroll
        for (int q = 0; q < 4; ++q) {
            int li = q * 256 + tid;
            int v  = li >> 4;
            int wd = 2 * (li & 15);
            float4 f1 = g1[li];
            float4 f2 = g2[li];
            Wa1[v * SW + wd]     = pkh(f1.x, f1.y);
            Wa1[v * SW + wd + 1] = pkh(f1.z, f1.w);
            Wa2[v * SW + wd]     = pkh(f2.x, f2.y);
            Wa2[v * SW + wd + 1] = pkh(f2.z, f2.w);
        }

        const float* __restrict__ w0  = W0 + s * 64;
        const float* __restrict__ bb0 = b0 + s * 64;
#pragma unroll
        for (int j = 0; j < 16; j += 2) {
            int v = 16 * wv + j;
            float h0 = tanh_fast(fmaf(w0[v],     x, bb0[v]));
            float h1 = tanh_fast(fmaf(w0[v + 1], x, bb0[v + 1]));
            HtA[lane * SW + (v >> 1)] = pkh(h0, h1);
        }
        __syncthreads();

        const int vbase = 16 * wv + 4 * quad;
        f32x4 acc[4];

        // ---- layer 1 (MFMA)
        {
            const float* __restrict__ b1g = b1 + s * 64;
            float bv[4];
#pragma unroll
            for (int r = 0; r < 4; ++r) bv[r] = b1g[vbase + r];
#pragma unroll
            for (int ni = 0; ni < 4; ++ni)
#pragma unroll
                for (int r = 0; r < 4; ++r) acc[ni][r] = bv[r];

            half8 afr[2];
#pragma unroll
            for (int ks = 0; ks < 2; ++ks)
                afr[ks] = *(const half8*)&Wa1[(16 * wv + a16) * SW + 16 * ks + 4 * quad];
#pragma unroll
            for (int ni = 0; ni < 4; ++ni) {
#pragma unroll
                for (int ks = 0; ks < 2; ++ks) {
                    half8 bfr = *(const half8*)&HtA[(16 * ni + a16) * SW + 16 * ks + 4 * quad];
                    acc[ni] = __builtin_amdgcn_mfma_f32_16x16x32_f16(afr[ks], bfr, acc[ni], 0, 0, 0);
                }
            }
#pragma unroll
            for (int ni = 0; ni < 4; ++ni) {
                int row  = (16 * ni + a16) * SW;
                int colb = 8 * wv + 2 * quad;
                HtB[row + colb]     = pkh(tanh_fast(acc[ni][0]), tanh_fast(acc[ni][1]));
                HtB[row + colb + 1] = pkh(tanh_fast(acc[ni][2]), tanh_fast(acc[ni][3]));
            }
        }
        __syncthreads();

        // ---- layer 2 (MFMA)
        {
            const float* __restrict__ b2g = b2 + s * 64;
            float bv[4];
#pragma unroll
            for (int r = 0; r < 4; ++r) bv[r] = b2g[vbase + r];
#pragma unroll
            for (int ni = 0; ni < 4; ++ni)
#pragma unroll
                for (int r = 0; r < 4; ++r) acc[ni][r] = bv[r];

            half8 afr[2];
#pragma unroll
            for (int ks = 0; ks < 2; ++ks)
                afr[ks] = *(const half8*)&Wa2[(16 * wv + a16) * SW + 16 * ks + 4 * quad];
#pragma unroll
            for (int ni = 0; ni < 4; ++ni) {
#pragma unroll
                for (int ks = 0; ks < 2; ++ks) {
                    half8 bfr = *(const half8*)&HtB[(16 * ni + a16) * SW + 16 * ks + 4 * quad];
                    acc[ni] = __builtin_amdgcn_mfma_f32_16x16x32_f16(afr[ks], bfr, acc[ni], 0, 0, 0);
                }
            }
        }

        // ---- layer 3
        {
            const float* __restrict__ w3g = W3 + s * 64;
            float w3r[4];
#pragma unroll
            for (int r = 0; r < 4; ++r) w3r[r] = w3g[vbase + r];
#pragma unroll
            for (int ni = 0; ni < 4; ++ni) {
                float pu = 0.0f;
#pragma unroll
                for (int r = 0; r < 4; ++r)
                    pu = fmaf(w3r[r], tanh_fast(acc[ni][r]), pu);
                pu += __shfl_xor(pu, 16);
                pu += __shfl_xor(pu, 32);
                if (quad == 0) Pw[wv][ni][a16] = pu;
            }
        }
        __syncthreads();

        if (tid < 64) {
            float u = b3[s];
#pragma unroll
            for (int w = 0; w < 4; ++w) u += Pw[w][tid >> 4][tid & 15];
            U[s * WIDTH + chunk * 64 + tid] = u;
        }
    }

    grid_barrier(b);                            // U visible everywhere

    // ============ Phase C: per-point PoU combine + hard BC (r9 math) =======
    {
        int n = b * 256 + tid;
        float x = x_in[n];

        int jf = (int)floorf(x * 63.0f);
        int lo = jf - 5;
        lo = lo < 0 ? 0 : (lo > 52 ? 52 : lo);

        const float inv_sigma = 64.0f / 1.5f;
        const float t_all = x * (float)GK;

        float u0v[12], u1v[12], fracv[12], wvv[12];
#pragma unroll
        for (int k = 0; k < 12; ++k) {
            int s = lo + k;
            int glo = glo_of(s);
            float t = t_all - (float)glo;
            int it = (int)floorf(t);
            it = it < 0 ? 0 : (it > WIDTH - 2 ? WIDTH - 2 : it);
            fracv[k] = t - (float)it;
            const float* __restrict__ row = U + s * WIDTH + it;
            u0v[k] = row[0];
            u1v[k] = row[1];
            float d = (x - (float)s * (1.0f / 63.0f)) * inv_sigma;
            wvv[k] = __expf(-0.5f * d * d);
        }

        float num = 0.0f, den = 0.0f;
#pragma unroll
        for (int k = 0; k < 12; ++k) {
            float u = fmaf(fracv[k], u1v[k] - u0v[k], u0v[k]);
            num = fmaf(wvv[k], u, num);
            den += wvv[k];
        }

        out[n] = tanh_fast(5.0f * x) * num * __builtin_amdgcn_rcpf(den);
    }
}

// ---------------------------------------------------------------------------
extern "C" void kernel_launch(void* const* d_in, const int* in_sizes, int n_in,
                              void* d_out, int out_size, void* d_ws, size_t ws_size,
                              hipStream_t stream) {
    const float* x  = (const float*)d_in[0];
    const float* W0 = (const float*)d_in[1];
    const float* b0 = (const float*)d_in[2];
    const float* W1 = (const float*)d_in[3];
    const float* b1 = (const float*)d_in[4];
    const float* W2 = (const float*)d_in[5];
    const float* b2 = (const float*)d_in[6];
    const float* W3 = (const float*)d_in[7];
    const float* b3 = (const float*)d_in[8];

    float* U   = (float*)d_ws;              // 64*256*4 B = 64 KiB
    float* out = (float*)d_out;

    fbpinn_fused<<<dim3(NB), dim3(256), 0, stream>>>(
        x, W0, b0, W1, b1, W2, b2, W3, b3, U, out);
}

// Round 14
// 75.330 us; speedup vs baseline: 2.1972x; 1.6610x over previous
//
#include <hip/hip_runtime.h>
#include <math.h>

// FBPINN PoU: S=64 subdomains, N=65536 points, W=64.
// Round 14: TWO kernels (was 3). r12/r13 proved software grid barriers cost
// ~50 us on this part regardless of topology -> fusion dead. r13's residual
// pinned the harness floor at ~64 us; r11's 3 kernels + gaps = ~14 us
// controllable. This round removes one graph node: drop the F-table and do
// the r9-verified direct 12-subnet combine as kernel 2.
//   eval_grid: r11 verbatim. MFMA f16 layers 1/2; GK=1280, WIDTH=256;
//              block = (subdomain, 64-pt chunk) = 256 blocks.
//   combine:   per-point 12-subnet Gaussian PoU + lerp from U + hard BC.

#define GK     1280
#define WIDTH  256
#define HALFW  128
#define SW     36      // u32 words per LDS row: 32 data + 4 pad = 144 B

typedef _Float16 half8  __attribute__((ext_vector_type(8)));
typedef __fp16   fp16x2 __attribute__((ext_vector_type(2)));
typedef float    f32x4  __attribute__((ext_vector_type(4)));

__device__ __forceinline__ int glo_of(int s) {
    int g = (s * GK + 31) / 63 - HALFW;
    g = g < 0 ? 0 : g;
    const int hi = GK - (WIDTH - 1);
    g = g > hi ? hi : g;
    return g;
}

__device__ __forceinline__ float tanh_fast(float v) {
    // tanh(v) = 1 - 2/(exp(2v)+1); |v| <= ~7 here.
    float e = __expf(2.0f * v);
    return 1.0f - 2.0f * __builtin_amdgcn_rcpf(e + 1.0f);
}

__device__ __forceinline__ unsigned pkh(float a, float b) {
    fp16x2 h = __builtin_amdgcn_cvt_pkrtz(a, b);   // a->lo, b->hi
    return __builtin_bit_cast(unsigned, h);
}

// ---------------------------------------------------------------------------
// Kernel 1: eval subnet tables. 64 subdomains x 4 chunks = 256 blocks.
// ---------------------------------------------------------------------------
__global__ __launch_bounds__(256, 4) void eval_grid(
    const float* __restrict__ W0, const float* __restrict__ b0,
    const float* __restrict__ W1, const float* __restrict__ b1,
    const float* __restrict__ W2, const float* __restrict__ b2,
    const float* __restrict__ W3, const float* __restrict__ b3,
    float* __restrict__ U)
{
    const int tid  = (int)threadIdx.x;
    const int lane = tid & 63;
    const int wv   = __builtin_amdgcn_readfirstlane(tid >> 6);
    const int quad = lane >> 4;
    const int a16  = lane & 15;

    const int s     = blockIdx.x & 63;
    const int chunk = blockIdx.x >> 6;           // 0..3
    const int glo   = glo_of(s);
    const float x   = (float)(glo + chunk * 64 + lane) * (1.0f / (float)GK);

    __shared__ unsigned HtA[64 * SW];   // h0, f16-pairs, rows = p
    __shared__ unsigned HtB[64 * SW];   // h1
    __shared__ unsigned Wa1[64 * SW];   // W1 f16, rows = v (A layout)
    __shared__ unsigned Wa2[64 * SW];
    __shared__ float    Pw[4][4][16];   // layer-3 partials [wv][ni][a16]

    // ---- stage W1, W2 as f16 rows (coalesced float4 loads)
    const float4* __restrict__ g1 = (const float4*)(W1 + s * 4096);
    const float4* __restrict__ g2 = (const float4*)(W2 + s * 4096);
#pragma unroll
    for (int q = 0; q < 4; ++q) {
        int li = q * 256 + tid;              // float4 index 0..1023
        int v  = li >> 4;                    // row
        int wd = 2 * (li & 15);              // word col
        float4 f1 = g1[li];
        float4 f2 = g2[li];
        Wa1[v * SW + wd]     = pkh(f1.x, f1.y);
        Wa1[v * SW + wd + 1] = pkh(f1.z, f1.w);
        Wa2[v * SW + wd]     = pkh(f2.x, f2.y);
        Wa2[v * SW + wd + 1] = pkh(f2.z, f2.w);
    }

    // ---- layer 0
    const float* __restrict__ w0  = W0 + s * 64;
    const float* __restrict__ bb0 = b0 + s * 64;
#pragma unroll
    for (int j = 0; j < 16; j += 2) {
        int v = 16 * wv + j;
        float h0 = tanh_fast(fmaf(w0[v],     x, bb0[v]));
        float h1 = tanh_fast(fmaf(w0[v + 1], x, bb0[v + 1]));
        HtA[lane * SW + (v >> 1)] = pkh(h0, h1);
    }
    __syncthreads();                         // h0 + Wa1 + Wa2 visible

    const int vbase = 16 * wv + 4 * quad;
    f32x4 acc[4];

    // ================= layer 1 (MFMA) =================
    {
        const float* __restrict__ b1g = b1 + s * 64;
        float bv[4];
#pragma unroll
        for (int r = 0; r < 4; ++r) bv[r] = b1g[vbase + r];
#pragma unroll
        for (int ni = 0; ni < 4; ++ni)
#pragma unroll
            for (int r = 0; r < 4; ++r) acc[ni][r] = bv[r];

        half8 afr[2];
#pragma unroll
        for (int ks = 0; ks < 2; ++ks)
            afr[ks] = *(const half8*)&Wa1[(16 * wv + a16) * SW + 16 * ks + 4 * quad];
#pragma unroll
        for (int ni = 0; ni < 4; ++ni) {
#pragma unroll
            for (int ks = 0; ks < 2; ++ks) {
                half8 bfr = *(const half8*)&HtA[(16 * ni + a16) * SW + 16 * ks + 4 * quad];
                acc[ni] = __builtin_amdgcn_mfma_f32_16x16x32_f16(afr[ks], bfr, acc[ni], 0, 0, 0);
            }
        }
#pragma unroll
        for (int ni = 0; ni < 4; ++ni) {
            int row  = (16 * ni + a16) * SW;
            int colb = 8 * wv + 2 * quad;
            HtB[row + colb]     = pkh(tanh_fast(acc[ni][0]), tanh_fast(acc[ni][1]));
            HtB[row + colb + 1] = pkh(tanh_fast(acc[ni][2]), tanh_fast(acc[ni][3]));
        }
    }
    __syncthreads();                         // h1 visible

    // ================= layer 2 (MFMA) =================
    {
        const float* __restrict__ b2g = b2 + s * 64;
        float bv[4];
#pragma unroll
        for (int r = 0; r < 4; ++r) bv[r] = b2g[vbase + r];
#pragma unroll
        for (int ni = 0; ni < 4; ++ni)
#pragma unroll
            for (int r = 0; r < 4; ++r) acc[ni][r] = bv[r];

        half8 afr[2];
#pragma unroll
        for (int ks = 0; ks < 2; ++ks)
            afr[ks] = *(const half8*)&Wa2[(16 * wv + a16) * SW + 16 * ks + 4 * quad];
#pragma unroll
        for (int ni = 0; ni < 4; ++ni) {
#pragma unroll
            for (int ks = 0; ks < 2; ++ks) {
                half8 bfr = *(const half8*)&HtB[(16 * ni + a16) * SW + 16 * ks + 4 * quad];
                acc[ni] = __builtin_amdgcn_mfma_f32_16x16x32_f16(afr[ks], bfr, acc[ni], 0, 0, 0);
            }
        }
    }

    // ================= layer 3 =================
    {
        const float* __restrict__ w3g = W3 + s * 64;
        float w3r[4];
#pragma unroll
        for (int r = 0; r < 4; ++r) w3r[r] = w3g[vbase + r];
#pragma unroll
        for (int ni = 0; ni < 4; ++ni) {
            float pu = 0.0f;
#pragma unroll
            for (int r = 0; r < 4; ++r)
                pu = fmaf(w3r[r], tanh_fast(acc[ni][r]), pu);
            pu += __shfl_xor(pu, 16);
            pu += __shfl_xor(pu, 32);
            if (quad == 0) Pw[wv][ni][a16] = pu;
        }
    }
    __syncthreads();

    if (tid < 64) {
        float u = b3[s];
#pragma unroll
        for (int w = 0; w < 4; ++w) u += Pw[w][tid >> 4][tid & 15];
        U[s * WIDTH + chunk * 64 + tid] = u;
    }
}

// ---------------------------------------------------------------------------
// Kernel 2: per-point 12-subnet Gaussian PoU combine + hard BC (r9 math).
// ---------------------------------------------------------------------------
__global__ __launch_bounds__(256) void combine(
    const float* __restrict__ x_in, const float* __restrict__ U,
    float* __restrict__ out, int N)
{
    int n = blockIdx.x * 256 + (int)threadIdx.x;
    if (n >= N) return;
    float x = x_in[n];

    int jf = (int)floorf(x * 63.0f);
    int lo = jf - 5;
    lo = lo < 0 ? 0 : (lo > 52 ? 52 : lo);

    const float inv_sigma = 64.0f / 1.5f;
    const float t_all = x * (float)GK;

    float u0v[12], u1v[12], fracv[12], wvv[12];
#pragma unroll
    for (int k = 0; k < 12; ++k) {
        int s = lo + k;
        int glo = glo_of(s);
        float t = t_all - (float)glo;
        int it = (int)floorf(t);
        it = it < 0 ? 0 : (it > WIDTH - 2 ? WIDTH - 2 : it);
        fracv[k] = t - (float)it;
        const float* __restrict__ row = U + s * WIDTH + it;
        u0v[k] = row[0];
        u1v[k] = row[1];
        float d = (x - (float)s * (1.0f / 63.0f)) * inv_sigma;
        wvv[k] = __expf(-0.5f * d * d);
    }

    float num = 0.0f, den = 0.0f;
#pragma unroll
    for (int k = 0; k < 12; ++k) {
        float u = fmaf(fracv[k], u1v[k] - u0v[k], u0v[k]);
        num = fmaf(wvv[k], u, num);
        den += wvv[k];
    }

    out[n] = tanh_fast(5.0f * x) * num * __builtin_amdgcn_rcpf(den);
}

// ---------------------------------------------------------------------------
extern "C" void kernel_launch(void* const* d_in, const int* in_sizes, int n_in,
                              void* d_out, int out_size, void* d_ws, size_t ws_size,
                              hipStream_t stream) {
    const float* x  = (const float*)d_in[0];
    const float* W0 = (const float*)d_in[1];
    const float* b0 = (const float*)d_in[2];
    const float* W1 = (const float*)d_in[3];
    const float* b1 = (const float*)d_in[4];
    const float* W2 = (const float*)d_in[5];
    const float* b2 = (const float*)d_in[6];
    const float* W3 = (const float*)d_in[7];
    const float* b3 = (const float*)d_in[8];

    float* U   = (float*)d_ws;              // 64*256*4 B = 64 KiB
    float* out = (float*)d_out;

    eval_grid<<<dim3(256), dim3(256), 0, stream>>>(
        W0, b0, W1, b1, W2, b2, W3, b3, U);
    combine<<<dim3(256), dim3(256), 0, stream>>>(x, U, out, 65536);
}